// Round 1
// baseline (979.712 us; speedup 1.0000x reference)
//
#include <hip/hip_runtime.h>
#include <math.h>

// ---------------- threefry2x32 (JAX-compatible, 20 rounds) ----------------
struct TFOut { unsigned a, b; };

__host__ __device__ constexpr TFOut tf2x32(unsigned k0, unsigned k1,
                                           unsigned x0, unsigned x1) {
  unsigned ks2 = k0 ^ k1 ^ 0x1BD11BDAu;
  unsigned ks[3] = {k0, k1, ks2};
  const int R0[4] = {13, 15, 26, 6};
  const int R1[4] = {17, 29, 16, 24};
  x0 += ks[0]; x1 += ks[1];
  for (int i = 0; i < 5; ++i) {
    const int* R = (i & 1) ? R1 : R0;
    for (int j = 0; j < 4; ++j) {
      x0 += x1;
      x1 = (x1 << R[j]) | (x1 >> (32 - R[j]));
      x1 ^= x0;
    }
    x0 += ks[(i + 1) % 3];
    x1 += ks[(i + 2) % 3] + (unsigned)(i + 1);
  }
  return {x0, x1};
}

// jax.random.key(42) -> raw key (0,42); split with threefry_partitionable=True:
// key_i = threefry(key, hi=0, lo=i) (both output words form the derived key)
constexpr TFOut KEY1 = tf2x32(0u, 42u, 0u, 0u);  // phase key
constexpr TFOut KEY2 = tf2x32(0u, 42u, 0u, 1u);  // intensity key

// ---------------- gumbel helpers ----------------
__device__ inline float bits_to_g(unsigned bits) {
  // JAX uniform(key, shape, f32, 1e-10, 1.0):
  //   f = bitcast(bits>>9 | 0x3f800000) - 1 ; f = max(1e-10, f*1.0 + 1e-10)
  float f = __uint_as_float((bits >> 9) | 0x3f800000u) - 1.0f;
  f = f + 1e-10f;
  f = fmaxf(1e-10f, f);
  // g = -log(-log(f)), each log rounded to f32 (double for correct rounding)
  float l1 = (float)log((double)f);
  float l2 = (float)log((double)(-l1));
  return -l2;
}

__device__ inline unsigned long long packcand(float val, int p) {
  unsigned u = __float_as_uint(val);
  u = (u & 0x80000000u) ? ~u : (u | 0x80000000u);  // order-preserving map
  return ((unsigned long long)u << 32) | (unsigned)(255 - p);  // tie -> low idx
}

// one block per pixel; 256 threads = 256 gumbel channels
__global__ __launch_bounds__(256) void gumbel_kernel(
    const float* __restrict__ voltage, const float* __restrict__ phase_func,
    const float* __restrict__ intensity_func, float2* __restrict__ PT) {
  const int q = blockIdx.x;   // pixel index < 40000
  const int p = threadIdx.x;  // channel
  const unsigned idx = (unsigned)q * 256u + (unsigned)p;  // flat (S,S,P) index
  const float v = voltage[(size_t)q * 256 + p];
  // partitionable random_bits (32-bit): bits = out0 ^ out1 of tf(key, 0, idx)
  TFOut r1 = tf2x32(KEY1.a, KEY1.b, 0u, idx);
  TFOut r2 = tf2x32(KEY2.a, KEY2.b, 0u, idx);
  float g1 = bits_to_g(r1.a ^ r1.b);
  float g2 = bits_to_g(r2.a ^ r2.b);
  float c1 = (v + g1) / 10.0f;  // /tau as in reference (f32 divide)
  float c2 = (v + g2) / 10.0f;

  __shared__ unsigned long long red[2];
  if (p < 2) red[p] = 0ull;
  __syncthreads();
  atomicMax(&red[0], packcand(c1, p));
  atomicMax(&red[1], packcand(c2, p));
  __syncthreads();
  if (p == 0) {
    int i1 = 255 - (int)(red[0] & 0xFFFFFFFFull);
    int i2 = 255 - (int)(red[1] & 0xFFFFFFFFull);
    float phi = phase_func[i1];
    float amp = intensity_func[i2] * 6.0f;
    PT[q] = make_float2(amp * cosf(phi), amp * sinf(phi));
  }
}

// ---------------- DFT tables + packing ----------------
__global__ __launch_bounds__(256) void build_tables(
    const float* __restrict__ h_real, const float* __restrict__ h_imag,
    float2* __restrict__ F, float2* __restrict__ G, float2* __restrict__ Hc) {
  int idx = blockIdx.x * 256 + threadIdx.x;
  if (idx >= 40000) return;
  int j = idx / 200;
  int k = idx - j * 200;
  int m = (j * k) % 200;
  double ang = -2.0 * 3.14159265358979323846 * (double)m / 200.0;
  double c = cos(ang), s = sin(ang);
  F[idx] = make_float2((float)c, (float)s);                       // exp(-i2pi jk/200)
  G[idx] = make_float2((float)(c * 0.005), (float)(-s * 0.005));  // conj(F)/200
  Hc[idx] = make_float2(h_real[idx], h_imag[idx]);
}

__global__ __launch_bounds__(256) void pack_waves(
    const float* __restrict__ re, const float* __restrict__ im,
    float2* __restrict__ W) {
  int idx = blockIdx.x * 256 + threadIdx.x;  // grid exact: 2500*256 = 640000
  W[idx] = make_float2(re[idx], im[idx]);
}

// ---------------- batched complex GEMM: C[b] = A[b] @ (B[b] .* MB) ----------------
// row-major float2; 32x32 tile, BK=8, 2x2 per thread, bounds-checked
__global__ __launch_bounds__(256) void cgemm(
    const float2* __restrict__ A, long sA, const float2* __restrict__ B, long sB,
    float2* __restrict__ C, long sC, const float2* __restrict__ MB,
    int M, int N, int K) {
  __shared__ __align__(16) float2 As[8][32];  // [k][m]
  __shared__ __align__(16) float2 Bs[8][32];  // [k][n]
  const int tid = threadIdx.x;
  const long bz = blockIdx.z;
  A += bz * sA; B += bz * sB; C += bz * sC;
  const int tx = tid & 15;   // n-dir
  const int ty = tid >> 4;   // m-dir
  const int row0 = blockIdx.x * 32 + ty * 2;
  const int col0 = blockIdx.y * 32 + tx * 2;

  float2 acc00 = {0, 0}, acc01 = {0, 0}, acc10 = {0, 0}, acc11 = {0, 0};

  const int am = blockIdx.x * 32 + (tid >> 3);
  const int ak_off = tid & 7;
  const int bn = blockIdx.y * 32 + (tid & 31);
  const int bk_off = tid >> 5;

  for (int k0 = 0; k0 < K; k0 += 8) {
    int ak = k0 + ak_off;
    float2 av = {0, 0};
    if (am < M && ak < K) av = A[(long)am * K + ak];
    As[ak_off][tid >> 3] = av;

    int bk = k0 + bk_off;
    float2 bv = {0, 0};
    if (bk < K && bn < N) {
      bv = B[(long)bk * N + bn];
      if (MB) {
        float2 hm = MB[(long)bk * N + bn];
        bv = make_float2(bv.x * hm.x - bv.y * hm.y, bv.x * hm.y + bv.y * hm.x);
      }
    }
    Bs[bk_off][tid & 31] = bv;
    __syncthreads();
#pragma unroll
    for (int kk = 0; kk < 8; ++kk) {
      float4 a = *(const float4*)&As[kk][ty * 2];
      float4 b = *(const float4*)&Bs[kk][tx * 2];
      acc00.x = fmaf(a.x, b.x, fmaf(-a.y, b.y, acc00.x));
      acc00.y = fmaf(a.x, b.y, fmaf(a.y, b.x, acc00.y));
      acc01.x = fmaf(a.x, b.z, fmaf(-a.y, b.w, acc01.x));
      acc01.y = fmaf(a.x, b.w, fmaf(a.y, b.z, acc01.y));
      acc10.x = fmaf(a.z, b.x, fmaf(-a.w, b.y, acc10.x));
      acc10.y = fmaf(a.z, b.y, fmaf(a.w, b.x, acc10.y));
      acc11.x = fmaf(a.z, b.z, fmaf(-a.w, b.w, acc11.x));
      acc11.y = fmaf(a.z, b.w, fmaf(a.w, b.z, acc11.y));
    }
    __syncthreads();
  }
  if (row0 < M) {
    if (col0 < N) C[(long)row0 * N + col0] = acc00;
    if (col0 + 1 < N) C[(long)row0 * N + col0 + 1] = acc01;
  }
  if (row0 + 1 < M) {
    if (col0 < N) C[(long)(row0 + 1) * N + col0] = acc10;
    if (col0 + 1 < N) C[(long)(row0 + 1) * N + col0 + 1] = acc11;
  }
}

// ---------------- phase multiply + 10x pixel expansion ----------------
// out (B,2000,2000,2) f32; one float4 = 2 output pixels per thread.
// c even => both pixels of a float4 share the same source block column j.
__global__ __launch_bounds__(256) void expand_kernel(
    const float2* __restrict__ Xc, const float2* __restrict__ PT,
    float4* __restrict__ out) {
  unsigned q = blockIdx.x * 256u + threadIdx.x;  // < 32,000,000 (exact grid)
  unsigned p0 = q * 2u;
  unsigned b = p0 / 4000000u;
  unsigned rem = p0 - b * 4000000u;
  unsigned r = rem / 2000u;
  unsigned c0 = rem - r * 2000u;
  unsigned i = r / 10u;
  unsigned dr = r - i * 10u;
  float4 o = {0.f, 0.f, 0.f, 0.f};
  if (dr - 1u <= 7u) {  // dr in [1,8]
    unsigned j = c0 / 10u;
    unsigned dc = c0 - j * 10u;  // even: 0,2,4,6,8
    float2 xv = Xc[b * 40000u + i * 200u + j];
    float2 pt = PT[i * 200u + j];
    float re = xv.x * pt.x - xv.y * pt.y;
    float im = xv.x * pt.y + xv.y * pt.x;
    if (dc != 0u) { o.x = re; o.y = im; }
    if (dc != 8u) { o.z = re; o.w = im; }
  }
  out[q] = o;
}

// ---------------- launch ----------------
extern "C" void kernel_launch(void* const* d_in, const int* in_sizes, int n_in,
                              void* d_out, int out_size, void* d_ws, size_t ws_size,
                              hipStream_t stream) {
  const float* waves_real = (const float*)d_in[0];
  const float* waves_imag = (const float*)d_in[1];
  const float* h_real = (const float*)d_in[2];
  const float* h_imag = (const float*)d_in[3];
  const float* voltage = (const float*)d_in[4];
  const float* phase_func = (const float*)d_in[5];
  const float* intensity_func = (const float*)d_in[6];

  float2* F  = (float2*)d_ws;       // 40000
  float2* G  = F + 40000;           // 40000
  float2* Hc = G + 40000;           // 40000
  float2* PT = Hc + 40000;          // 40000
  float2* Wc = PT + 40000;          // 640000
  float2* T1 = Wc + 640000;         // 640000
  float2* T2 = T1 + 640000;         // 640000
  float2* T4 = T2 + 640000;         // 640000
  float2* Xc = T4 + 640000;         // 640000  (total ~26.9 MB)

  build_tables<<<157, 256, 0, stream>>>(h_real, h_imag, F, G, Hc);
  pack_waves<<<2500, 256, 0, stream>>>(waves_real, waves_imag, Wc);
  gumbel_kernel<<<40000, 256, 0, stream>>>(voltage, phase_func, intensity_func, PT);

  dim3 gBat(7, 7, 16);    // M=200 tiles x N=200 tiles x batch
  dim3 gFlat(100, 7, 1);  // M=3200 tiles x N=200 tiles

  // T1_b = F @ W_b            (fft along axis 0)
  cgemm<<<gBat, 256, 0, stream>>>(F, 0, Wc, 40000, T1, 40000, nullptr, 200, 200, 200);
  // T2 = T1(3200x200) @ F     (fft along axis 1)
  cgemm<<<gFlat, 256, 0, stream>>>(T1, 0, F, 0, T2, 0, nullptr, 3200, 200, 200);
  // T4_b = G @ (T2_b .* h)    (ifft axis 0, h fused, 1/200 folded in G)
  cgemm<<<gBat, 256, 0, stream>>>(G, 0, T2, 40000, T4, 40000, Hc, 200, 200, 200);
  // Xc = T4(3200x200) @ G     (ifft axis 1, 1/200 folded in G)
  cgemm<<<gFlat, 256, 0, stream>>>(T4, 0, G, 0, Xc, 0, nullptr, 3200, 200, 200);

  expand_kernel<<<125000, 256, 0, stream>>>(Xc, PT, (float4*)d_out);
}

// Round 2
// 876.223 us; speedup vs baseline: 1.1181x; 1.1181x over previous
//
#include <hip/hip_runtime.h>
#include <math.h>

// ---------------- threefry2x32 (JAX-compatible, 20 rounds) ----------------
struct TFOut { unsigned a, b; };

__host__ __device__ constexpr TFOut tf2x32(unsigned k0, unsigned k1,
                                           unsigned x0, unsigned x1) {
  unsigned ks2 = k0 ^ k1 ^ 0x1BD11BDAu;
  unsigned ks[3] = {k0, k1, ks2};
  const int R0[4] = {13, 15, 26, 6};
  const int R1[4] = {17, 29, 16, 24};
  x0 += ks[0]; x1 += ks[1];
  for (int i = 0; i < 5; ++i) {
    const int* R = (i & 1) ? R1 : R0;
    for (int j = 0; j < 4; ++j) {
      x0 += x1;
      x1 = (x1 << R[j]) | (x1 >> (32 - R[j]));
      x1 ^= x0;
    }
    x0 += ks[(i + 1) % 3];
    x1 += ks[(i + 2) % 3] + (unsigned)(i + 1);
  }
  return {x0, x1};
}

constexpr TFOut KEY1 = tf2x32(0u, 42u, 0u, 0u);  // phase key
constexpr TFOut KEY2 = tf2x32(0u, 42u, 0u, 1u);  // intensity key

// ---------------- gumbel helpers ----------------
__device__ inline float bits_to_u(unsigned bits) {
  float f = __uint_as_float((bits >> 9) | 0x3f800000u) - 1.0f;
  f = f + 1e-10f;
  return fmaxf(1e-10f, f);
}

// exact path: each log correctly rounded to f32 via double (baseline-identical)
__device__ inline float u_to_g_exact(float u) {
  float l1 = (float)log((double)u);
  float l2 = (float)log((double)(-l1));
  return -l2;
}

// fast path: precise ocml logf (<=1 ulp); |g_fast - g_exact| <~ 2.3e-6
__device__ inline float u_to_g_fast(float u) {
  float l1 = logf(u);
  float l2 = logf(-l1);
  return -l2;
}

__device__ inline unsigned ordf(float f) {  // order-preserving float->uint
  unsigned u = __float_as_uint(f);
  return (u & 0x80000000u) ? ~u : (u | 0x80000000u);
}
__device__ inline float unordf(unsigned u) {
  return (u & 0x80000000u) ? __uint_as_float(u ^ 0x80000000u)
                           : __uint_as_float(~u);
}

__device__ inline unsigned long long packcand(float val, int p) {
  return ((unsigned long long)ordf(val) << 32) | (unsigned)(255 - p);  // tie -> low idx
}

// one block per pixel; 256 threads = 256 gumbel channels
__global__ __launch_bounds__(256) void gumbel_kernel(
    const float* __restrict__ voltage, const float* __restrict__ phase_func,
    const float* __restrict__ intensity_func, float2* __restrict__ PT) {
  const int q = blockIdx.x;   // pixel index < 40000
  const int p = threadIdx.x;  // channel
  const unsigned idx = (unsigned)q * 256u + (unsigned)p;
  const float v = voltage[(size_t)q * 256 + p];
  TFOut r1 = tf2x32(KEY1.a, KEY1.b, 0u, idx);
  TFOut r2 = tf2x32(KEY2.a, KEY2.b, 0u, idx);
  const float u1 = bits_to_u(r1.a ^ r1.b);
  const float u2 = bits_to_u(r2.a ^ r2.b);
  // fast approx comparison values
  const float c1a = (v + u_to_g_fast(u1)) * 0.1f;
  const float c2a = (v + u_to_g_fast(u2)) * 0.1f;

  __shared__ unsigned smax[2];
  __shared__ unsigned long long red[2];
  if (p < 2) { smax[p] = 0u; red[p] = 0ull; }
  __syncthreads();
  atomicMax(&smax[0], ordf(c1a));
  atomicMax(&smax[1], ordf(c2a));
  __syncthreads();
  const float eps = 1e-5f;  // >> fast-path error bound (~2.3e-6 in c)
  const float m1 = unordf(smax[0]) - eps;
  const float m2 = unordf(smax[1]) - eps;
  // only near-max candidates (usually exactly 1) take the exact double path;
  // their exact values reproduce the baseline argmax bit-for-bit.
  if (c1a >= m1) {
    float c1 = (v + u_to_g_exact(u1)) / 10.0f;
    atomicMax(&red[0], packcand(c1, p));
  }
  if (c2a >= m2) {
    float c2 = (v + u_to_g_exact(u2)) / 10.0f;
    atomicMax(&red[1], packcand(c2, p));
  }
  __syncthreads();
  if (p == 0) {
    int i1 = 255 - (int)(red[0] & 0xFFFFFFFFull);
    int i2 = 255 - (int)(red[1] & 0xFFFFFFFFull);
    float phi = phase_func[i1];
    float amp = intensity_func[i2] * 6.0f;
    PT[q] = make_float2(amp * cosf(phi), amp * sinf(phi));
  }
}

// ---------------- DFT tables + packing ----------------
__global__ __launch_bounds__(256) void build_tables(
    const float* __restrict__ h_real, const float* __restrict__ h_imag,
    float2* __restrict__ F, float2* __restrict__ G, float2* __restrict__ Hc) {
  int idx = blockIdx.x * 256 + threadIdx.x;
  if (idx >= 40000) return;
  int j = idx / 200;
  int k = idx - j * 200;
  int m = (j * k) % 200;
  double ang = -2.0 * 3.14159265358979323846 * (double)m / 200.0;
  double c = cos(ang), s = sin(ang);
  F[idx] = make_float2((float)c, (float)s);                       // exp(-i2pi jk/200)
  G[idx] = make_float2((float)(c * 0.005), (float)(-s * 0.005));  // conj(F)/200
  Hc[idx] = make_float2(h_real[idx], h_imag[idx]);
}

__global__ __launch_bounds__(256) void pack_waves(
    const float* __restrict__ re, const float* __restrict__ im,
    float2* __restrict__ W) {
  int idx = blockIdx.x * 256 + threadIdx.x;  // grid exact: 2500*256 = 640000
  W[idx] = make_float2(re[idx], im[idx]);
}

// ---------------- batched complex GEMM: C[b] = A[b] @ (B[b] .* MB) ----------------
// row-major float2; 64x64 tile, BK=16, 4x4 complex acc per thread
__global__ __launch_bounds__(256) void cgemm(
    const float2* __restrict__ A, long sA, const float2* __restrict__ B, long sB,
    float2* __restrict__ C, long sC, const float2* __restrict__ MB,
    int M, int N, int K) {
  __shared__ __align__(16) float2 As[16][64];  // [k][m]
  __shared__ __align__(16) float2 Bs[16][64];  // [k][n]
  const int tid = threadIdx.x;
  const long bz = blockIdx.z;
  A += bz * sA; B += bz * sB; C += bz * sC;
  const int rowBase = blockIdx.x * 64;
  const int colBase = blockIdx.y * 64;

  // staging thread mapping (all bounds are 4-granular)
  const int a_m = tid >> 2;          // 0..63
  const int a_k4 = (tid & 3) * 4;    // 0,4,8,12
  const int b_k = tid >> 4;          // 0..15
  const int b_n4 = (tid & 15) * 4;   // 0..60

  const int tx4 = (tid & 15) * 4;    // col offset
  const int ty4 = (tid >> 4) * 4;    // row offset

  float2 acc[4][4];
#pragma unroll
  for (int i = 0; i < 4; ++i)
#pragma unroll
    for (int j = 0; j < 4; ++j) acc[i][j] = make_float2(0.f, 0.f);

  for (int k0 = 0; k0 < K; k0 += 16) {
    // global loads (issued before the barrier so they overlap prior compute)
    const int gm = rowBase + a_m;
    const int gka = k0 + a_k4;
    float4 av0 = {0, 0, 0, 0}, av1 = {0, 0, 0, 0};
    if (gm < M && gka < K) av0 = *(const float4*)&A[(long)gm * K + gka];
    if (gm < M && gka + 2 < K) av1 = *(const float4*)&A[(long)gm * K + gka + 2];

    const int gkb = k0 + b_k;
    const int gn = colBase + b_n4;
    float4 bv0 = {0, 0, 0, 0}, bv1 = {0, 0, 0, 0};
    if (gkb < K && gn < N) {
      bv0 = *(const float4*)&B[(long)gkb * N + gn];
      bv1 = *(const float4*)&B[(long)gkb * N + gn + 2];
      if (MB) {
        float4 h0 = *(const float4*)&MB[(long)gkb * N + gn];
        float4 h1 = *(const float4*)&MB[(long)gkb * N + gn + 2];
        bv0 = make_float4(bv0.x * h0.x - bv0.y * h0.y, bv0.x * h0.y + bv0.y * h0.x,
                          bv0.z * h0.z - bv0.w * h0.w, bv0.z * h0.w + bv0.w * h0.z);
        bv1 = make_float4(bv1.x * h1.x - bv1.y * h1.y, bv1.x * h1.y + bv1.y * h1.x,
                          bv1.z * h1.z - bv1.w * h1.w, bv1.z * h1.w + bv1.w * h1.z);
      }
    }
    __syncthreads();  // previous compute done before LDS overwrite
    As[a_k4 + 0][a_m] = make_float2(av0.x, av0.y);
    As[a_k4 + 1][a_m] = make_float2(av0.z, av0.w);
    As[a_k4 + 2][a_m] = make_float2(av1.x, av1.y);
    As[a_k4 + 3][a_m] = make_float2(av1.z, av1.w);
    *(float4*)&Bs[b_k][b_n4] = bv0;
    *(float4*)&Bs[b_k][b_n4 + 2] = bv1;
    __syncthreads();
#pragma unroll
    for (int kk = 0; kk < 16; ++kk) {
      float4 aA = *(const float4*)&As[kk][ty4];
      float4 aB = *(const float4*)&As[kk][ty4 + 2];
      float4 bA = *(const float4*)&Bs[kk][tx4];
      float4 bB = *(const float4*)&Bs[kk][tx4 + 2];
      float2 a[4] = {{aA.x, aA.y}, {aA.z, aA.w}, {aB.x, aB.y}, {aB.z, aB.w}};
      float2 b[4] = {{bA.x, bA.y}, {bA.z, bA.w}, {bB.x, bB.y}, {bB.z, bB.w}};
#pragma unroll
      for (int i = 0; i < 4; ++i)
#pragma unroll
        for (int j = 0; j < 4; ++j) {
          acc[i][j].x = fmaf(a[i].x, b[j].x, fmaf(-a[i].y, b[j].y, acc[i][j].x));
          acc[i][j].y = fmaf(a[i].x, b[j].y, fmaf(a[i].y, b[j].x, acc[i][j].y));
        }
    }
  }
#pragma unroll
  for (int rr = 0; rr < 4; ++rr) {
    const int r = rowBase + ty4 + rr;
    const int cb = colBase + tx4;
    if (r < M && cb < N) {
      *(float4*)&C[(long)r * N + cb] = make_float4(acc[rr][0].x, acc[rr][0].y,
                                                   acc[rr][1].x, acc[rr][1].y);
      *(float4*)&C[(long)r * N + cb + 2] = make_float4(acc[rr][2].x, acc[rr][2].y,
                                                       acc[rr][3].x, acc[rr][3].y);
    }
  }
}

// ---------------- phase multiply + 10x pixel expansion ----------------
__global__ __launch_bounds__(256) void expand_kernel(
    const float2* __restrict__ Xc, const float2* __restrict__ PT,
    float4* __restrict__ out) {
  unsigned q = blockIdx.x * 256u + threadIdx.x;  // < 32,000,000 (exact grid)
  unsigned p0 = q * 2u;
  unsigned b = p0 / 4000000u;
  unsigned rem = p0 - b * 4000000u;
  unsigned r = rem / 2000u;
  unsigned c0 = rem - r * 2000u;
  unsigned i = r / 10u;
  unsigned dr = r - i * 10u;
  float4 o = {0.f, 0.f, 0.f, 0.f};
  if (dr - 1u <= 7u) {  // dr in [1,8]
    unsigned j = c0 / 10u;
    unsigned dc = c0 - j * 10u;  // even: 0,2,4,6,8
    float2 xv = Xc[b * 40000u + i * 200u + j];
    float2 pt = PT[i * 200u + j];
    float re = xv.x * pt.x - xv.y * pt.y;
    float im = xv.x * pt.y + xv.y * pt.x;
    if (dc != 0u) { o.x = re; o.y = im; }
    if (dc != 8u) { o.z = re; o.w = im; }
  }
  out[q] = o;
}

// ---------------- launch ----------------
extern "C" void kernel_launch(void* const* d_in, const int* in_sizes, int n_in,
                              void* d_out, int out_size, void* d_ws, size_t ws_size,
                              hipStream_t stream) {
  const float* waves_real = (const float*)d_in[0];
  const float* waves_imag = (const float*)d_in[1];
  const float* h_real = (const float*)d_in[2];
  const float* h_imag = (const float*)d_in[3];
  const float* voltage = (const float*)d_in[4];
  const float* phase_func = (const float*)d_in[5];
  const float* intensity_func = (const float*)d_in[6];

  float2* F  = (float2*)d_ws;       // 40000
  float2* G  = F + 40000;           // 40000
  float2* Hc = G + 40000;           // 40000
  float2* PT = Hc + 40000;          // 40000
  float2* Wc = PT + 40000;          // 640000
  float2* T1 = Wc + 640000;         // 640000
  float2* T2 = T1 + 640000;         // 640000
  float2* T4 = T2 + 640000;         // 640000
  float2* Xc = T4 + 640000;         // 640000  (total ~26.9 MB)

  build_tables<<<157, 256, 0, stream>>>(h_real, h_imag, F, G, Hc);
  pack_waves<<<2500, 256, 0, stream>>>(waves_real, waves_imag, Wc);
  gumbel_kernel<<<40000, 256, 0, stream>>>(voltage, phase_func, intensity_func, PT);

  dim3 gBat(4, 4, 16);    // ceil(200/64) x ceil(200/64) x batch
  dim3 gFlat(50, 4, 1);   // ceil(3200/64) x ceil(200/64)

  // T1_b = F @ W_b            (fft along axis 0)
  cgemm<<<gBat, 256, 0, stream>>>(F, 0, Wc, 40000, T1, 40000, nullptr, 200, 200, 200);
  // T2 = T1(3200x200) @ F     (fft along axis 1)
  cgemm<<<gFlat, 256, 0, stream>>>(T1, 0, F, 0, T2, 0, nullptr, 3200, 200, 200);
  // T4_b = G @ (T2_b .* h)    (ifft axis 0, h fused, 1/200 folded in G)
  cgemm<<<gBat, 256, 0, stream>>>(G, 0, T2, 40000, T4, 40000, Hc, 200, 200, 200);
  // Xc = T4(3200x200) @ G     (ifft axis 1, 1/200 folded in G)
  cgemm<<<gFlat, 256, 0, stream>>>(T4, 0, G, 0, Xc, 0, nullptr, 3200, 200, 200);

  expand_kernel<<<125000, 256, 0, stream>>>(Xc, PT, (float4*)d_out);
}